// Round 4
// baseline (1343.050 us; speedup 1.0000x reference)
//
#include <hip/hip_runtime.h>

// Q4_0 SwiGLU FFN, MI355X. dim=4096, hidden=11008, M=4096 tokens.
// Round 6: round 5 (typed-LDS ds_read_b128 fragment reads) with the staging
// offset bug fixed: second 64-row strip goes to _d + 4096 ELEMENTS (8192 B),
// round 5 wrote _d + 2048 (a byte->element conversion error that overlapped
// strips and left 1/4 of each half-tile uninitialized -> NaN).
// 256x256 8-phase schedule (BK=64, 8 waves, 128KiB LDS double buffer, raw
// s_barrier + counted vmcnt(4), XOR swizzle both-sides, setprio) unchanged.

typedef __bf16 bf16;
typedef __bf16 bf16x4 __attribute__((ext_vector_type(4)));
typedef __bf16 bf16x8 __attribute__((ext_vector_type(8)));
typedef float  f32x4  __attribute__((ext_vector_type(4)));

__device__ __forceinline__ void gload_lds16(const bf16* g, bf16* l) {
  __builtin_amdgcn_global_load_lds(
      (__attribute__((address_space(1))) void*)(g),
      (__attribute__((address_space(3))) void*)(l), 16, 0, 0);
}

// ------------------------------------------------------------- x -> bf16 ---
__global__ void f32_to_bf16_k(const float* __restrict__ x,
                              bf16* __restrict__ y, int n4) {
  int t = blockIdx.x * blockDim.x + threadIdx.x;
  if (t >= n4) return;
  float4 v = ((const float4*)x)[t];
  bf16x4 o;
  o[0] = (bf16)v.x; o[1] = (bf16)v.y; o[2] = (bf16)v.z; o[3] = (bf16)v.w;
  ((bf16x4*)y)[t] = o;
}

// ---------------------------------------------- Q4_0 -> bf16 (row/K slice) --
__global__ void dq_k(const int* __restrict__ Wq, const float* __restrict__ S,
                     bf16* __restrict__ Wd, int r0, int rows, int kc0, int Kc,
                     int Ksrc) {
  const int tpr = Kc >> 5;  // 16-int32 thread-chunks per row-slice
  int t = blockIdx.x * blockDim.x + threadIdx.x;
  if (t >= rows * tpr) return;
  const int n = t / tpr;
  const int o = (t - n * tpr) << 4;  // local int32 offset in [0, Kc/2)
  const int gn = r0 + n;
  const int blk = o >> 6;            // local 128-k block
  const int j = o & 63;
  const int gblk = (kc0 >> 7) + blk;
  const int* src = Wq + (size_t)gn * (Ksrc >> 1) + (kc0 >> 1) + o;
  const float sm = S[(size_t)gn * (Ksrc >> 6) + 2 * gblk];
  const float sl = S[(size_t)gn * (Ksrc >> 6) + 2 * gblk + 1];
  int4 q0 = ((const int4*)src)[0];
  int4 q1 = ((const int4*)src)[1];
  int4 q2 = ((const int4*)src)[2];
  int4 q3 = ((const int4*)src)[3];
  int qa[16] = {q0.x, q0.y, q0.z, q0.w, q1.x, q1.y, q1.z, q1.w,
                q2.x, q2.y, q2.z, q2.w, q3.x, q3.y, q3.z, q3.w};
  bf16x8 m0, m1, l0, l1;
#pragma unroll
  for (int i = 0; i < 16; i++) {
    float fm_ = (float)(qa[i] >> 4) * sm;               // arithmetic: [-8,8)
    float fl_ = (float)(((qa[i] & 0xF) ^ 8) - 8) * sl;  // sign-extend nibble
    if (i < 8) { m0[i] = (bf16)fm_;     l0[i] = (bf16)fl_; }
    else       { m1[i - 8] = (bf16)fm_; l1[i - 8] = (bf16)fl_; }
  }
  bf16* dst = Wd + (size_t)n * Kc + (blk << 7) + j;
  *(bf16x8*)(dst)      = m0;
  *(bf16x8*)(dst + 8)  = m1;
  *(bf16x8*)(dst + 64) = l0;
  *(bf16x8*)(dst + 72) = l1;
}

// ------------------------------------- 256^2 8-phase GEMM (m201 template) --
// C(MxN) = A(MxK) * B(nloc x K)^T.  8 waves (2Mx4N), per-wave 128x64 out.
// LDS [buf][A|B][256 rows][64 cols] bf16, XOR-swizzled (16B slot ^= row&7)
// via pre-swizzled global source + swizzled ds_read (same involution).
// EPI: 0 = f32 store, 1 = bf16 store, 2 = G = silu(acc)*G, 3 = f32 add.
template <int EPI>
__launch_bounds__(512, 2)
__global__ void gemm8_k(const bf16* __restrict__ A, int lda,
                        const bf16* __restrict__ B, int ldb,
                        bf16* __restrict__ G, float* __restrict__ Fout,
                        int M, int Nglob, int K, int n0g) {
  __shared__ __attribute__((aligned(16))) bf16 lds[65536];  // 128 KiB

  const int tid  = threadIdx.x;
  const int lane = tid & 63;
  const int wave = tid >> 6;
  const int wr = wave >> 2;      // 0..1 -> M half
  const int wc = wave & 3;       // 0..3 -> N quarter
  const int fm = lane & 15;
  const int fq = lane >> 4;
  const int m0 = blockIdx.y * 256;
  const int n0 = blockIdx.x * 256;  // chunk-local

  // staging geometry: one STG = 2 strips of (512 thr x 16B = 64 rows x 128B),
  // linear LDS dest, source column pre-swizzled by the read involution.
  const int srow = tid >> 3;                        // row within 64-row strip
  const int scol = ((tid & 7) ^ (srow & 7)) << 3;   // bf16 col (swizzled src)
  const bf16* Abase = A + (size_t)(m0 + srow) * lda + scol;
  const bf16* Bbase = B + (size_t)(n0 + srow) * ldb + scol;

  // fragment read addressing, ELEMENT units (typed LDS -> ds_read_b128).
  // buffer bb at elem bb*32768; A rows at row*64; B region at +16384.
  // 16B slot swizzle: slot ^= (row&7); row&7 == fm&7 (row bases mult of 16).
  const int arow_e = (wr * 128 + fm) * 64;
  const int brow_e = 16384 + (wc * 64 + fm) * 64;
  const int eck0 = ((fq)     ^ (fm & 7)) << 3;  // k-half 0, elems
  const int eck1 = ((4 + fq) ^ (fm & 7)) << 3;  // k-half 1, elems

  f32x4 acc[8][4] = {};
  bf16x8 ar[4][2], bl[2][2], bh[2][2];

#define STG_A(bb, h, kt) do {                                             \
    const bf16* _s = Abase + (size_t)((h) * 128) * lda + (size_t)(kt) * 64;\
    bf16* _d = lds + (bb) * 32768 + (h) * 8192 + tid * 8;                 \
    gload_lds16(_s, _d);                                                  \
    gload_lds16(_s + (size_t)64 * lda, _d + 4096);                        \
  } while (0)
#define STG_B(bb, h, kt) do {                                             \
    const bf16* _s = Bbase + (size_t)((h) * 128) * ldb + (size_t)(kt) * 64;\
    bf16* _d = lds + (bb) * 32768 + 16384 + (h) * 8192 + tid * 8;         \
    gload_lds16(_s, _d);                                                  \
    gload_lds16(_s + (size_t)64 * ldb, _d + 4096);                        \
  } while (0)
#define RDA(bb, i0) { _Pragma("unroll")                                   \
    for (int ii = 0; ii < 4; ii++) {                                      \
      ar[ii][0] = *(const bf16x8*)&lds[(bb) * 32768 + arow_e + ((i0) + ii) * 1024 + eck0]; \
      ar[ii][1] = *(const bf16x8*)&lds[(bb) * 32768 + arow_e + ((i0) + ii) * 1024 + eck1]; } }
#define RDB(dst, bb, j0) { _Pragma("unroll")                              \
    for (int jj = 0; jj < 2; jj++) {                                      \
      dst[jj][0] = *(const bf16x8*)&lds[(bb) * 32768 + brow_e + ((j0) + jj) * 1024 + eck0]; \
      dst[jj][1] = *(const bf16x8*)&lds[(bb) * 32768 + brow_e + ((j0) + jj) * 1024 + eck1]; } }
#define MFM(i0, j0, bsrc) {                                               \
    __builtin_amdgcn_s_setprio(1);                                        \
    _Pragma("unroll") for (int ii = 0; ii < 4; ii++)                      \
    _Pragma("unroll") for (int jj = 0; jj < 2; jj++) {                    \
      acc[(i0) + ii][(j0) + jj] = __builtin_amdgcn_mfma_f32_16x16x32_bf16(\
          ar[ii][0], bsrc[jj][0], acc[(i0) + ii][(j0) + jj], 0, 0, 0);    \
      acc[(i0) + ii][(j0) + jj] = __builtin_amdgcn_mfma_f32_16x16x32_bf16(\
          ar[ii][1], bsrc[jj][1], acc[(i0) + ii][(j0) + jj], 0, 0, 0); }  \
    __builtin_amdgcn_s_setprio(0); }
#define BAR { __builtin_amdgcn_sched_barrier(0); __builtin_amdgcn_s_barrier(); \
              __builtin_amdgcn_sched_barrier(0); }
#define VM4 { __builtin_amdgcn_sched_barrier(0);                          \
              asm volatile("s_waitcnt vmcnt(4)");                         \
              __builtin_amdgcn_sched_barrier(0); }

  const int NT = K >> 6;  // K-tiles of 64, NT even (K % 128 == 0)

  // Prologue: tile0 (B0,A0,B1,A1 -> buf0) + tile1 (B0,A0 -> buf1);
  // wait tile0's 8 loads (leave 4 in flight) -- matches steady-state.
  STG_B(0, 0, 0); STG_A(0, 0, 0); STG_B(0, 1, 0); STG_A(0, 1, 0);
  STG_B(1, 0, 1); STG_A(1, 0, 1);
  VM4; BAR;

  for (int it = 0; it < (NT >> 1); ++it) {
    const int t = 2 * it;
    const int kt2 = (t + 2 < NT) ? t + 2 : 0;  // wrap: staged, never consumed
    const int kt3 = (t + 3 < NT) ? t + 3 : 1;
    // ---- K-tile t (buf0): quadrants (ilo,jlo)(ilo,jhi)(ihi,jhi)(ihi,jlo)
    RDA(0, 0); RDB(bl, 0, 0); STG_B(1, 1, t + 1); BAR; MFM(0, 0, bl); BAR;  // P1
    RDB(bh, 0, 2);            STG_A(1, 1, t + 1); BAR; MFM(0, 2, bh); BAR;  // P2
    RDA(0, 4);                STG_B(0, 0, kt2);   BAR; MFM(4, 2, bh); BAR;  // P3
                              STG_A(0, 0, kt2); VM4; BAR; MFM(4, 0, bl); BAR; // P4
    // ---- K-tile t+1 (buf1)
    RDA(1, 0); RDB(bl, 1, 0); STG_B(0, 1, kt2);   BAR; MFM(0, 0, bl); BAR;  // P5
    RDB(bh, 1, 2);            STG_A(0, 1, kt2);   BAR; MFM(0, 2, bh); BAR;  // P6
    RDA(1, 4);                STG_B(1, 0, kt3);   BAR; MFM(4, 2, bh); BAR;  // P7
                              STG_A(1, 0, kt3); VM4; BAR; MFM(4, 0, bl); BAR; // P8
  }

  // --- epilogue. C/D: col = fm, row = fq*4 + r.
#pragma unroll
  for (int i = 0; i < 8; i++) {
    const int row = m0 + wr * 128 + i * 16 + fq * 4;
#pragma unroll
    for (int j = 0; j < 4; j++) {
      const int col = n0g + n0 + wc * 64 + j * 16 + fm;
#pragma unroll
      for (int r = 0; r < 4; r++) {
        const size_t idx = (size_t)(row + r) * Nglob + col;
        if constexpr (EPI == 0) {
          Fout[idx] = acc[i][j][r];
        } else if constexpr (EPI == 1) {
          G[idx] = (bf16)acc[i][j][r];
        } else if constexpr (EPI == 2) {
          float a = acc[i][j][r];
          float g = (float)G[idx];
          G[idx] = (bf16)((a / (1.0f + __expf(-a))) * g);
        } else {
          Fout[idx] += acc[i][j][r];
        }
      }
    }
  }
#undef STG_A
#undef STG_B
#undef RDA
#undef RDB
#undef MFM
#undef BAR
#undef VM4
}

// ----------------------------------------- fallback: dequant-fused GEMM ----
#define BM 128
#define BN 128
#define BK 32
#define BSTR 40
template <int EPI>
__launch_bounds__(256)
__global__ void gemm_dq_k(const bf16* __restrict__ A,
                          const int* __restrict__ Wq,
                          const float* __restrict__ S,
                          bf16* __restrict__ G,
                          float* __restrict__ Fout,
                          int M, int N, int K) {
  __shared__ __attribute__((aligned(16))) bf16 As[BM * BK];
  __shared__ __attribute__((aligned(16))) bf16 Bs[BN * BSTR];
  const int tid  = threadIdx.x;
  const int lane = tid & 63;
  const int wave = tid >> 6;
  const int n0 = blockIdx.x * BN;
  const int m0 = blockIdx.y * BM;
  const int o0 = tid * 16, o1 = tid * 16 + 4096;
  const bf16* a0 = A + (size_t)(m0 + (o0 >> 6)) * K + ((o0 & 63) >> 1);
  const bf16* a1 = A + (size_t)(m0 + (o1 >> 6)) * K + ((o1 & 63) >> 1);
  bf16* lA0 = As + (o0 >> 1);
  bf16* lA1 = As + (o1 >> 1);
  const int rr  = tid >> 1;
  const int seg = (tid & 1) * 16;
  const int nrow = n0 + rr;
  const int* wrow = Wq + (size_t)nrow * (K >> 1);
  const float* srow = S + (size_t)nrow * (K >> 6);
  bf16* bdst = Bs + rr * BSTR + seg;
  const int fm = lane & 15;
  const int fq = lane >> 4;
  const int wm = (wave >> 1) * 64;
  const int wn = (wave & 1) * 64;
  f32x4 acc[4][4] = {};
  for (int k0 = 0; k0 < K; k0 += BK) {
    gload_lds16(a0, lA0);
    gload_lds16(a1, lA1);
    a0 += BK; a1 += BK;
    const int kk = k0 + seg;
    const int* wp = wrow + ((kk >> 7) << 6) + (kk & 63);
    int4 q0 = ((const int4*)wp)[0];
    int4 q1 = ((const int4*)wp)[1];
    int4 q2 = ((const int4*)wp)[2];
    int4 q3 = ((const int4*)wp)[3];
    const float sc = srow[kk >> 6];
    const int sh = ((kk & 127) < 64) ? 4 : 0;
    int qa[16] = {q0.x, q0.y, q0.z, q0.w, q1.x, q1.y, q1.z, q1.w,
                  q2.x, q2.y, q2.z, q2.w, q3.x, q3.y, q3.z, q3.w};
    bf16x8 lo, hi;
#pragma unroll
    for (int i = 0; i < 16; i++) {
      int v = (((qa[i] >> sh) & 0xF) ^ 8) - 8;
      float f = (float)v * sc;
      if (i < 8) lo[i] = (bf16)f;
      else       hi[i - 8] = (bf16)f;
    }
    *(bf16x8*)(bdst)     = lo;
    *(bf16x8*)(bdst + 8) = hi;
    __syncthreads();
    bf16x8 af[4], bfr[4];
#pragma unroll
    for (int i = 0; i < 4; i++)
      af[i] = *(const bf16x8*)&As[(wm + 16 * i + fm) * BK + fq * 8];
#pragma unroll
    for (int j = 0; j < 4; j++)
      bfr[j] = *(const bf16x8*)&Bs[(wn + 16 * j + fm) * BSTR + fq * 8];
#pragma unroll
    for (int i = 0; i < 4; i++)
#pragma unroll
      for (int j = 0; j < 4; j++)
        acc[i][j] = __builtin_amdgcn_mfma_f32_16x16x32_bf16(
            af[i], bfr[j], acc[i][j], 0, 0, 0);
    __syncthreads();
  }
#pragma unroll
  for (int i = 0; i < 4; i++) {
    const int row0 = m0 + wm + 16 * i + fq * 4;
#pragma unroll
    for (int j = 0; j < 4; j++) {
      const int col = n0 + wn + 16 * j + fm;
#pragma unroll
      for (int r = 0; r < 4; r++) {
        size_t idx = (size_t)(row0 + r) * N + col;
        if constexpr (EPI == 0) {
          Fout[idx] = acc[i][j][r];
        } else if constexpr (EPI == 1) {
          G[idx] = (bf16)acc[i][j][r];
        } else {
          float a = acc[i][j][r];
          float g = (float)G[idx];
          G[idx] = (bf16)((a / (1.0f + __expf(-a))) * g);
        }
      }
    }
  }
}

// ------------------------------------------------------------------ launch --
extern "C" void kernel_launch(void* const* d_in, const int* in_sizes, int n_in,
                              void* d_out, int out_size, void* d_ws,
                              size_t ws_size, hipStream_t stream) {
  const float* x  = (const float*)d_in[0];
  const int*   w1 = (const int*)d_in[1];
  const float* s1 = (const float*)d_in[2];
  const int*   w2 = (const int*)d_in[3];
  const float* s2 = (const float*)d_in[4];
  const int*   w3 = (const int*)d_in[5];
  const float* s3 = (const float*)d_in[6];
  float* out = (float*)d_out;

  const int dim = 4096, hidden = 11008;
  const int M = in_sizes[0] / dim;  // 4096
  const int mt8 = M / 256;          // 16

  // ws: [G 90.2MB][Wd chunk]; Xb lives in d_out (dead before GEMM2).
  char* ws = (char*)d_ws;
  bf16* G  = (bf16*)ws;
  const size_t Gb = (size_t)M * hidden * 2;
  bf16* Wd = (bf16*)(ws + Gb);
  const size_t avail = (ws_size > Gb) ? ws_size - Gb : 0;
  bf16* Xb = (bf16*)d_out;

  const int nx4 = M * dim / 4;
  f32_to_bf16_k<<<(nx4 + 255) / 256, 256, 0, stream>>>(x, Xb, nx4);

  // ---- GEMM3 / GEMM1: N-chunks of 256-col tiles, K=dim ----
  const int NT1 = hidden / 256;               // 43
  const size_t tb1 = (size_t)256 * dim * 2;   // 2 MiB per tile
  int c1 = (int)(avail / tb1);
  if (c1 > NT1) c1 = NT1;

  if (c1 >= 1) {
    for (int pass = 0; pass < 2; ++pass) {
      const int*   w = pass ? w1 : w3;
      const float* s = pass ? s1 : s3;
      for (int t0 = 0; t0 < NT1; t0 += c1) {
        int nt = (NT1 - t0 < c1) ? NT1 - t0 : c1;
        int thr = nt * 256 * (dim >> 5);
        dq_k<<<(thr + 255) / 256, 256, 0, stream>>>(w, s, Wd, t0 * 256,
                                                    nt * 256, 0, dim, dim);
        if (pass == 0)
          gemm8_k<1><<<dim3(nt, mt8), 512, 0, stream>>>(
              Xb, dim, Wd, dim, G, nullptr, M, hidden, dim, t0 * 256);
        else
          gemm8_k<2><<<dim3(nt, mt8), 512, 0, stream>>>(
              Xb, dim, Wd, dim, G, nullptr, M, hidden, dim, t0 * 256);
      }
    }
  } else {
    dim3 gh(hidden / BN, M / BM);
    gemm_dq_k<1><<<gh, 256, 0, stream>>>(Xb, w3, s3, G, nullptr, M, hidden, dim);
    gemm_dq_k<2><<<gh, 256, 0, stream>>>(Xb, w1, s1, G, nullptr, M, hidden, dim);
  }

  // ---- GEMM2: K-chunks (full-width grid each launch), f32 accumulate ----
  long long kcl = (long long)(avail / ((size_t)dim * 2)) & ~127LL;
  int Kc = (kcl > hidden) ? hidden : (int)kcl;
  if (Kc >= 128) {
    int kc0 = 0;
    bool first = true;
    while (kc0 < hidden) {
      int kc = (hidden - kc0 < Kc) ? hidden - kc0 : Kc;  // multiple of 128
      int thr = dim * (kc >> 5);
      dq_k<<<(thr + 255) / 256, 256, 0, stream>>>(w2, s2, Wd, 0, dim, kc0, kc,
                                                  hidden);
      if (first)
        gemm8_k<0><<<dim3(dim / 256, mt8), 512, 0, stream>>>(
            G + kc0, hidden, Wd, kc, nullptr, out, M, dim, kc, 0);
      else
        gemm8_k<3><<<dim3(dim / 256, mt8), 512, 0, stream>>>(
            G + kc0, hidden, Wd, kc, nullptr, out, M, dim, kc, 0);
      first = false;
      kc0 += kc;
    }
  } else {
    dim3 gd(dim / BN, M / BM);
    gemm_dq_k<0><<<gd, 256, 0, stream>>>(G, w2, s2, nullptr, out, M, dim, hidden);
  }
}

// Round 5
// 1329.183 us; speedup vs baseline: 1.0104x; 1.0104x over previous
//
#include <hip/hip_runtime.h>

// Q4_0 SwiGLU FFN, MI355X. dim=4096, hidden=11008, M=4096 tokens.
// Round 7: + T1 bijective XCD-chunked blockIdx swizzle in gemm8_k (m204/m157).
// Diagnosis: FETCH_SIZE 906MB/dispatch vs 124MB unique = 7x refetch; linear
// blockIdx interleaves panels across the 8 XCD L2s. Swizzle gives each XCD a
// contiguous x-major block range -> A-panels L2-resident, B streams.
// Everything else identical to round 6 (passed, 1343us): 256x256 8-phase,
// BK=64, 8 waves, 128KiB LDS dbuf, counted vmcnt(4), XOR swizzle, setprio.

typedef __bf16 bf16;
typedef __bf16 bf16x4 __attribute__((ext_vector_type(4)));
typedef __bf16 bf16x8 __attribute__((ext_vector_type(8)));
typedef float  f32x4  __attribute__((ext_vector_type(4)));

__device__ __forceinline__ void gload_lds16(const bf16* g, bf16* l) {
  __builtin_amdgcn_global_load_lds(
      (__attribute__((address_space(1))) void*)(g),
      (__attribute__((address_space(3))) void*)(l), 16, 0, 0);
}

// ------------------------------------------------------------- x -> bf16 ---
__global__ void f32_to_bf16_k(const float* __restrict__ x,
                              bf16* __restrict__ y, int n4) {
  int t = blockIdx.x * blockDim.x + threadIdx.x;
  if (t >= n4) return;
  float4 v = ((const float4*)x)[t];
  bf16x4 o;
  o[0] = (bf16)v.x; o[1] = (bf16)v.y; o[2] = (bf16)v.z; o[3] = (bf16)v.w;
  ((bf16x4*)y)[t] = o;
}

// ---------------------------------------------- Q4_0 -> bf16 (row/K slice) --
__global__ void dq_k(const int* __restrict__ Wq, const float* __restrict__ S,
                     bf16* __restrict__ Wd, int r0, int rows, int kc0, int Kc,
                     int Ksrc) {
  const int tpr = Kc >> 5;  // 16-int32 thread-chunks per row-slice
  int t = blockIdx.x * blockDim.x + threadIdx.x;
  if (t >= rows * tpr) return;
  const int n = t / tpr;
  const int o = (t - n * tpr) << 4;  // local int32 offset in [0, Kc/2)
  const int gn = r0 + n;
  const int blk = o >> 6;            // local 128-k block
  const int j = o & 63;
  const int gblk = (kc0 >> 7) + blk;
  const int* src = Wq + (size_t)gn * (Ksrc >> 1) + (kc0 >> 1) + o;
  const float sm = S[(size_t)gn * (Ksrc >> 6) + 2 * gblk];
  const float sl = S[(size_t)gn * (Ksrc >> 6) + 2 * gblk + 1];
  int4 q0 = ((const int4*)src)[0];
  int4 q1 = ((const int4*)src)[1];
  int4 q2 = ((const int4*)src)[2];
  int4 q3 = ((const int4*)src)[3];
  int qa[16] = {q0.x, q0.y, q0.z, q0.w, q1.x, q1.y, q1.z, q1.w,
                q2.x, q2.y, q2.z, q2.w, q3.x, q3.y, q3.z, q3.w};
  bf16x8 m0, m1, l0, l1;
#pragma unroll
  for (int i = 0; i < 16; i++) {
    float fm_ = (float)(qa[i] >> 4) * sm;               // arithmetic: [-8,8)
    float fl_ = (float)(((qa[i] & 0xF) ^ 8) - 8) * sl;  // sign-extend nibble
    if (i < 8) { m0[i] = (bf16)fm_;     l0[i] = (bf16)fl_; }
    else       { m1[i - 8] = (bf16)fm_; l1[i - 8] = (bf16)fl_; }
  }
  bf16* dst = Wd + (size_t)n * Kc + (blk << 7) + j;
  *(bf16x8*)(dst)      = m0;
  *(bf16x8*)(dst + 8)  = m1;
  *(bf16x8*)(dst + 64) = l0;
  *(bf16x8*)(dst + 72) = l1;
}

// ------------------------------------- 256^2 8-phase GEMM (m201 template) --
// C(MxN) = A(MxK) * B(nloc x K)^T.  8 waves (2Mx4N), per-wave 128x64 out.
// LDS [buf][A|B][256 rows][64 cols] bf16, XOR-swizzled (16B slot ^= row&7)
// via pre-swizzled global source + swizzled ds_read (same involution).
// T1: XCD-chunked bijective blockIdx swizzle (grid x*y % 8 == 0 always here).
// EPI: 0 = f32 store, 1 = bf16 store, 2 = G = silu(acc)*G, 3 = f32 add.
template <int EPI>
__launch_bounds__(512, 2)
__global__ void gemm8_k(const bf16* __restrict__ A, int lda,
                        const bf16* __restrict__ B, int ldb,
                        bf16* __restrict__ G, float* __restrict__ Fout,
                        int M, int Nglob, int K, int n0g) {
  __shared__ __attribute__((aligned(16))) bf16 lds[65536];  // 128 KiB

  const int tid  = threadIdx.x;
  const int lane = tid & 63;
  const int wave = tid >> 6;
  const int wr = wave >> 2;      // 0..1 -> M half
  const int wc = wave & 3;       // 0..3 -> N quarter
  const int fm = lane & 15;
  const int fq = lane >> 4;

  // T1 XCD swizzle: linear x-major id -> each XCD owns a contiguous chunk.
  const int nwg = gridDim.x * gridDim.y;          // multiple of 8 (y = 16)
  const int wg  = blockIdx.y * gridDim.x + blockIdx.x;
  const int lin = (wg & 7) * (nwg >> 3) + (wg >> 3);
  const int bx  = lin % gridDim.x;
  const int by  = lin / gridDim.x;
  const int m0 = by * 256;
  const int n0 = bx * 256;  // chunk-local

  // staging geometry: one STG = 2 strips of (512 thr x 16B = 64 rows x 128B),
  // linear LDS dest, source column pre-swizzled by the read involution.
  const int srow = tid >> 3;                        // row within 64-row strip
  const int scol = ((tid & 7) ^ (srow & 7)) << 3;   // bf16 col (swizzled src)
  const bf16* Abase = A + (size_t)(m0 + srow) * lda + scol;
  const bf16* Bbase = B + (size_t)(n0 + srow) * ldb + scol;

  // fragment read addressing, ELEMENT units (typed LDS -> ds_read_b128).
  // buffer bb at elem bb*32768; A rows at row*64; B region at +16384.
  // 16B slot swizzle: slot ^= (row&7); row&7 == fm&7 (row bases mult of 16).
  const int arow_e = (wr * 128 + fm) * 64;
  const int brow_e = 16384 + (wc * 64 + fm) * 64;
  const int eck0 = ((fq)     ^ (fm & 7)) << 3;  // k-half 0, elems
  const int eck1 = ((4 + fq) ^ (fm & 7)) << 3;  // k-half 1, elems

  f32x4 acc[8][4] = {};
  bf16x8 ar[4][2], bl[2][2], bh[2][2];

#define STG_A(bb, h, kt) do {                                             \
    const bf16* _s = Abase + (size_t)((h) * 128) * lda + (size_t)(kt) * 64;\
    bf16* _d = lds + (bb) * 32768 + (h) * 8192 + tid * 8;                 \
    gload_lds16(_s, _d);                                                  \
    gload_lds16(_s + (size_t)64 * lda, _d + 4096);                        \
  } while (0)
#define STG_B(bb, h, kt) do {                                             \
    const bf16* _s = Bbase + (size_t)((h) * 128) * ldb + (size_t)(kt) * 64;\
    bf16* _d = lds + (bb) * 32768 + 16384 + (h) * 8192 + tid * 8;         \
    gload_lds16(_s, _d);                                                  \
    gload_lds16(_s + (size_t)64 * ldb, _d + 4096);                        \
  } while (0)
#define RDA(bb, i0) { _Pragma("unroll")                                   \
    for (int ii = 0; ii < 4; ii++) {                                      \
      ar[ii][0] = *(const bf16x8*)&lds[(bb) * 32768 + arow_e + ((i0) + ii) * 1024 + eck0]; \
      ar[ii][1] = *(const bf16x8*)&lds[(bb) * 32768 + arow_e + ((i0) + ii) * 1024 + eck1]; } }
#define RDB(dst, bb, j0) { _Pragma("unroll")                              \
    for (int jj = 0; jj < 2; jj++) {                                      \
      dst[jj][0] = *(const bf16x8*)&lds[(bb) * 32768 + brow_e + ((j0) + jj) * 1024 + eck0]; \
      dst[jj][1] = *(const bf16x8*)&lds[(bb) * 32768 + brow_e + ((j0) + jj) * 1024 + eck1]; } }
#define MFM(i0, j0, bsrc) {                                               \
    __builtin_amdgcn_s_setprio(1);                                        \
    _Pragma("unroll") for (int ii = 0; ii < 4; ii++)                      \
    _Pragma("unroll") for (int jj = 0; jj < 2; jj++) {                    \
      acc[(i0) + ii][(j0) + jj] = __builtin_amdgcn_mfma_f32_16x16x32_bf16(\
          ar[ii][0], bsrc[jj][0], acc[(i0) + ii][(j0) + jj], 0, 0, 0);    \
      acc[(i0) + ii][(j0) + jj] = __builtin_amdgcn_mfma_f32_16x16x32_bf16(\
          ar[ii][1], bsrc[jj][1], acc[(i0) + ii][(j0) + jj], 0, 0, 0); }  \
    __builtin_amdgcn_s_setprio(0); }
#define BAR { __builtin_amdgcn_sched_barrier(0); __builtin_amdgcn_s_barrier(); \
              __builtin_amdgcn_sched_barrier(0); }
#define VM4 { __builtin_amdgcn_sched_barrier(0);                          \
              asm volatile("s_waitcnt vmcnt(4)");                         \
              __builtin_amdgcn_sched_barrier(0); }

  const int NT = K >> 6;  // K-tiles of 64, NT even (K % 128 == 0)

  // Prologue: tile0 (B0,A0,B1,A1 -> buf0) + tile1 (B0,A0 -> buf1);
  // wait tile0's 8 loads (leave 4 in flight) -- matches steady-state.
  STG_B(0, 0, 0); STG_A(0, 0, 0); STG_B(0, 1, 0); STG_A(0, 1, 0);
  STG_B(1, 0, 1); STG_A(1, 0, 1);
  VM4; BAR;

  for (int it = 0; it < (NT >> 1); ++it) {
    const int t = 2 * it;
    const int kt2 = (t + 2 < NT) ? t + 2 : 0;  // wrap: staged, never consumed
    const int kt3 = (t + 3 < NT) ? t + 3 : 1;
    // ---- K-tile t (buf0): quadrants (ilo,jlo)(ilo,jhi)(ihi,jhi)(ihi,jlo)
    RDA(0, 0); RDB(bl, 0, 0); STG_B(1, 1, t + 1); BAR; MFM(0, 0, bl); BAR;  // P1
    RDB(bh, 0, 2);            STG_A(1, 1, t + 1); BAR; MFM(0, 2, bh); BAR;  // P2
    RDA(0, 4);                STG_B(0, 0, kt2);   BAR; MFM(4, 2, bh); BAR;  // P3
                              STG_A(0, 0, kt2); VM4; BAR; MFM(4, 0, bl); BAR; // P4
    // ---- K-tile t+1 (buf1)
    RDA(1, 0); RDB(bl, 1, 0); STG_B(0, 1, kt2);   BAR; MFM(0, 0, bl); BAR;  // P5
    RDB(bh, 1, 2);            STG_A(0, 1, kt2);   BAR; MFM(0, 2, bh); BAR;  // P6
    RDA(1, 4);                STG_B(1, 0, kt3);   BAR; MFM(4, 2, bh); BAR;  // P7
                              STG_A(1, 0, kt3); VM4; BAR; MFM(4, 0, bl); BAR; // P8
  }

  // --- epilogue. C/D: col = fm, row = fq*4 + r.
#pragma unroll
  for (int i = 0; i < 8; i++) {
    const int row = m0 + wr * 128 + i * 16 + fq * 4;
#pragma unroll
    for (int j = 0; j < 4; j++) {
      const int col = n0g + n0 + wc * 64 + j * 16 + fm;
#pragma unroll
      for (int r = 0; r < 4; r++) {
        const size_t idx = (size_t)(row + r) * Nglob + col;
        if constexpr (EPI == 0) {
          Fout[idx] = acc[i][j][r];
        } else if constexpr (EPI == 1) {
          G[idx] = (bf16)acc[i][j][r];
        } else if constexpr (EPI == 2) {
          float a = acc[i][j][r];
          float g = (float)G[idx];
          G[idx] = (bf16)((a / (1.0f + __expf(-a))) * g);
        } else {
          Fout[idx] += acc[i][j][r];
        }
      }
    }
  }
#undef STG_A
#undef STG_B
#undef RDA
#undef RDB
#undef MFM
#undef BAR
#undef VM4
}

// ----------------------------------------- fallback: dequant-fused GEMM ----
#define BM 128
#define BN 128
#define BK 32
#define BSTR 40
template <int EPI>
__launch_bounds__(256)
__global__ void gemm_dq_k(const bf16* __restrict__ A,
                          const int* __restrict__ Wq,
                          const float* __restrict__ S,
                          bf16* __restrict__ G,
                          float* __restrict__ Fout,
                          int M, int N, int K) {
  __shared__ __attribute__((aligned(16))) bf16 As[BM * BK];
  __shared__ __attribute__((aligned(16))) bf16 Bs[BN * BSTR];
  const int tid  = threadIdx.x;
  const int lane = tid & 63;
  const int wave = tid >> 6;
  const int n0 = blockIdx.x * BN;
  const int m0 = blockIdx.y * BM;
  const int o0 = tid * 16, o1 = tid * 16 + 4096;
  const bf16* a0 = A + (size_t)(m0 + (o0 >> 6)) * K + ((o0 & 63) >> 1);
  const bf16* a1 = A + (size_t)(m0 + (o1 >> 6)) * K + ((o1 & 63) >> 1);
  bf16* lA0 = As + (o0 >> 1);
  bf16* lA1 = As + (o1 >> 1);
  const int rr  = tid >> 1;
  const int seg = (tid & 1) * 16;
  const int nrow = n0 + rr;
  const int* wrow = Wq + (size_t)nrow * (K >> 1);
  const float* srow = S + (size_t)nrow * (K >> 6);
  bf16* bdst = Bs + rr * BSTR + seg;
  const int fm = lane & 15;
  const int fq = lane >> 4;
  const int wm = (wave >> 1) * 64;
  const int wn = (wave & 1) * 64;
  f32x4 acc[4][4] = {};
  for (int k0 = 0; k0 < K; k0 += BK) {
    gload_lds16(a0, lA0);
    gload_lds16(a1, lA1);
    a0 += BK; a1 += BK;
    const int kk = k0 + seg;
    const int* wp = wrow + ((kk >> 7) << 6) + (kk & 63);
    int4 q0 = ((const int4*)wp)[0];
    int4 q1 = ((const int4*)wp)[1];
    int4 q2 = ((const int4*)wp)[2];
    int4 q3 = ((const int4*)wp)[3];
    const float sc = srow[kk >> 6];
    const int sh = ((kk & 127) < 64) ? 4 : 0;
    int qa[16] = {q0.x, q0.y, q0.z, q0.w, q1.x, q1.y, q1.z, q1.w,
                  q2.x, q2.y, q2.z, q2.w, q3.x, q3.y, q3.z, q3.w};
    bf16x8 lo, hi;
#pragma unroll
    for (int i = 0; i < 16; i++) {
      int v = (((qa[i] >> sh) & 0xF) ^ 8) - 8;
      float f = (float)v * sc;
      if (i < 8) lo[i] = (bf16)f;
      else       hi[i - 8] = (bf16)f;
    }
    *(bf16x8*)(bdst)     = lo;
    *(bf16x8*)(bdst + 8) = hi;
    __syncthreads();
    bf16x8 af[4], bfr[4];
#pragma unroll
    for (int i = 0; i < 4; i++)
      af[i] = *(const bf16x8*)&As[(wm + 16 * i + fm) * BK + fq * 8];
#pragma unroll
    for (int j = 0; j < 4; j++)
      bfr[j] = *(const bf16x8*)&Bs[(wn + 16 * j + fm) * BSTR + fq * 8];
#pragma unroll
    for (int i = 0; i < 4; i++)
#pragma unroll
      for (int j = 0; j < 4; j++)
        acc[i][j] = __builtin_amdgcn_mfma_f32_16x16x32_bf16(
            af[i], bfr[j], acc[i][j], 0, 0, 0);
    __syncthreads();
  }
#pragma unroll
  for (int i = 0; i < 4; i++) {
    const int row0 = m0 + wm + 16 * i + fq * 4;
#pragma unroll
    for (int j = 0; j < 4; j++) {
      const int col = n0 + wn + 16 * j + fm;
#pragma unroll
      for (int r = 0; r < 4; r++) {
        size_t idx = (size_t)(row0 + r) * N + col;
        if constexpr (EPI == 0) {
          Fout[idx] = acc[i][j][r];
        } else if constexpr (EPI == 1) {
          G[idx] = (bf16)acc[i][j][r];
        } else {
          float a = acc[i][j][r];
          float g = (float)G[idx];
          G[idx] = (bf16)((a / (1.0f + __expf(-a))) * g);
        }
      }
    }
  }
}

// ------------------------------------------------------------------ launch --
extern "C" void kernel_launch(void* const* d_in, const int* in_sizes, int n_in,
                              void* d_out, int out_size, void* d_ws,
                              size_t ws_size, hipStream_t stream) {
  const float* x  = (const float*)d_in[0];
  const int*   w1 = (const int*)d_in[1];
  const float* s1 = (const float*)d_in[2];
  const int*   w2 = (const int*)d_in[3];
  const float* s2 = (const float*)d_in[4];
  const int*   w3 = (const int*)d_in[5];
  const float* s3 = (const float*)d_in[6];
  float* out = (float*)d_out;

  const int dim = 4096, hidden = 11008;
  const int M = in_sizes[0] / dim;  // 4096
  const int mt8 = M / 256;          // 16

  // ws: [G 90.2MB][Wd chunk]; Xb lives in d_out (dead before GEMM2).
  char* ws = (char*)d_ws;
  bf16* G  = (bf16*)ws;
  const size_t Gb = (size_t)M * hidden * 2;
  bf16* Wd = (bf16*)(ws + Gb);
  const size_t avail = (ws_size > Gb) ? ws_size - Gb : 0;
  bf16* Xb = (bf16*)d_out;

  const int nx4 = M * dim / 4;
  f32_to_bf16_k<<<(nx4 + 255) / 256, 256, 0, stream>>>(x, Xb, nx4);

  // ---- GEMM3 / GEMM1: N-chunks of 256-col tiles, K=dim ----
  const int NT1 = hidden / 256;               // 43
  const size_t tb1 = (size_t)256 * dim * 2;   // 2 MiB per tile
  int c1 = (int)(avail / tb1);
  if (c1 > NT1) c1 = NT1;

  if (c1 >= 1) {
    for (int pass = 0; pass < 2; ++pass) {
      const int*   w = pass ? w1 : w3;
      const float* s = pass ? s1 : s3;
      for (int t0 = 0; t0 < NT1; t0 += c1) {
        int nt = (NT1 - t0 < c1) ? NT1 - t0 : c1;
        int thr = nt * 256 * (dim >> 5);
        dq_k<<<(thr + 255) / 256, 256, 0, stream>>>(w, s, Wd, t0 * 256,
                                                    nt * 256, 0, dim, dim);
        if (pass == 0)
          gemm8_k<1><<<dim3(nt, mt8), 512, 0, stream>>>(
              Xb, dim, Wd, dim, G, nullptr, M, hidden, dim, t0 * 256);
        else
          gemm8_k<2><<<dim3(nt, mt8), 512, 0, stream>>>(
              Xb, dim, Wd, dim, G, nullptr, M, hidden, dim, t0 * 256);
      }
    }
  } else {
    dim3 gh(hidden / BN, M / BM);
    gemm_dq_k<1><<<gh, 256, 0, stream>>>(Xb, w3, s3, G, nullptr, M, hidden, dim);
    gemm_dq_k<2><<<gh, 256, 0, stream>>>(Xb, w1, s1, G, nullptr, M, hidden, dim);
  }

  // ---- GEMM2: K-chunks (full-width grid each launch), f32 accumulate ----
  long long kcl = (long long)(avail / ((size_t)dim * 2)) & ~127LL;
  int Kc = (kcl > hidden) ? hidden : (int)kcl;
  if (Kc >= 128) {
    int kc0 = 0;
    bool first = true;
    while (kc0 < hidden) {
      int kc = (hidden - kc0 < Kc) ? hidden - kc0 : Kc;  // multiple of 128
      int thr = dim * (kc >> 5);
      dq_k<<<(thr + 255) / 256, 256, 0, stream>>>(w2, s2, Wd, 0, dim, kc0, kc,
                                                  hidden);
      if (first)
        gemm8_k<0><<<dim3(dim / 256, mt8), 512, 0, stream>>>(
            G + kc0, hidden, Wd, kc, nullptr, out, M, dim, kc, 0);
      else
        gemm8_k<3><<<dim3(dim / 256, mt8), 512, 0, stream>>>(
            G + kc0, hidden, Wd, kc, nullptr, out, M, dim, kc, 0);
      first = false;
      kc0 += kc;
    }
  } else {
    dim3 gd(dim / BN, M / BM);
    gemm_dq_k<0><<<gd, 256, 0, stream>>>(G, w2, s2, nullptr, out, M, dim, hidden);
  }
}